// Round 4
// baseline (64.699 us; speedup 1.0000x reference)
//
#include <hip/hip_runtime.h>

// out[b, t, w, c] = x[b, t + w - 9, c] (zero outside [0, T)), x: [32, 4096, 30] f32.
// Per (b,t) the 570-float output row equals the contiguous x span starting at
// (t-9)*30. A pair of rows (t even, t+1) is 1140 floats = 285 float4 units,
// 16B-aligned. Each thread emits UNROLL 16B nontemporal stores (independent
// load->store chains for MLP), each built from two float2 loads (a float2
// never straddles a row: 570 is even; both lanes share one validity check).

typedef float f32x4 __attribute__((ext_vector_type(4)));

constexpr int B   = 32;
constexpr int T   = 4096;          // power of 2
constexpr int C   = 30;
constexpr int PAD = 9;             // W/2
constexpr int ROW = 570;           // W*C floats per output row
constexpr int TC  = T * C;         // 122880 floats per batch of x
constexpr int PAIR_F4 = 285;       // float4 units per row-pair (1140 floats)
constexpr unsigned NPAIRS = (unsigned)B * (T / 2);   // 65536 row-pairs
constexpr unsigned TOTAL4 = NPAIRS * PAIR_F4;        // 18,662,400 float4 units
constexpr int UNROLL = 4;
constexpr unsigned CHUNK = TOTAL4 / UNROLL;          // 4,665,600 (divides evenly)

__global__ __launch_bounds__(256)
void OverlapTimeWindowLayer_kernel(const float* __restrict__ x,
                                   f32x4* __restrict__ out) {
    const unsigned v0 = blockIdx.x * 256u + threadIdx.x;
#pragma unroll
    for (int k = 0; k < UNROLL; ++k) {
        const unsigned v = v0 + (unsigned)k * CHUNK;
        const unsigned p = v / PAIR_F4;            // row-pair index (magic-mul div)
        const int u  = (int)(v - p * PAIR_F4);     // float4 unit within pair [0,285)
        const int b  = (int)(p >> 11);             // / (T/2)
        const int tp = (int)(p & 2047);            // pair's first row is t = 2*tp
        const int base = (2 * tp - PAD) * C;       // source offset of row t
        const int e0 = 4 * u;                      // element offset within pair
        const float* xb = x + (unsigned)b * TC;

        // If element e >= ROW it belongs to row t+1: source -= (ROW - C).
        const int s0 = base + e0     - (e0     >= ROW ? (ROW - C) : 0);
        const int s1 = base + e0 + 2 - (e0 + 2 >= ROW ? (ROW - C) : 0);

        float2 lo = make_float2(0.0f, 0.0f);
        float2 hi = make_float2(0.0f, 0.0f);
        if (s0 >= 0 && s0 < TC) lo = *reinterpret_cast<const float2*>(xb + s0);
        if (s1 >= 0 && s1 < TC) hi = *reinterpret_cast<const float2*>(xb + s1);

        f32x4 val;
        val.x = lo.x; val.y = lo.y; val.z = hi.x; val.w = hi.y;
        __builtin_nontemporal_store(val, out + v);
    }
}

extern "C" void kernel_launch(void* const* d_in, const int* in_sizes, int n_in,
                              void* d_out, int out_size, void* d_ws, size_t ws_size,
                              hipStream_t stream) {
    const float* x = (const float*)d_in[0];
    f32x4* out = (f32x4*)d_out;
    const int block = 256;
    const unsigned grid = CHUNK / block;       // 18,225 blocks, exact
    OverlapTimeWindowLayer_kernel<<<grid, block, 0, stream>>>(x, out);
}

// Round 5
// 64.629 us; speedup vs baseline: 1.0011x; 1.0011x over previous
//
#include <hip/hip_runtime.h>

// out[b, t, w, c] = x[b, t + w - 9, c] (zero outside [0, T)), x: [32, 4096, 30] f32.
// Per (b,t) the 570-float output row equals the contiguous x span starting at
// (t-9)*30. A pair of rows (t even, t+1) is 1140 floats = 285 float4 units,
// 16B-aligned. Each thread emits exactly one 16B store (PLAIN write-back this
// round — A/B vs R3's nontemporal: fill kernels sustain 6.9 TB/s on this path)
// built from two float2 loads (a float2 never straddles a row: 570 is even;
// both lanes of a float2 share one validity predicate).

typedef float f32x4 __attribute__((ext_vector_type(4)));

constexpr int B   = 32;
constexpr int T   = 4096;          // power of 2
constexpr int C   = 30;
constexpr int PAD = 9;             // W/2
constexpr int ROW = 570;           // W*C floats per output row
constexpr int TC  = T * C;         // 122880 floats per batch of x
constexpr int PAIR_F4 = 285;       // float4 units per row-pair (1140 floats)
constexpr unsigned NPAIRS = (unsigned)B * (T / 2);   // 65536 row-pairs
constexpr unsigned TOTAL4 = NPAIRS * PAIR_F4;        // 18,662,400 float4 units

__global__ __launch_bounds__(256)
void OverlapTimeWindowLayer_kernel(const float* __restrict__ x,
                                   f32x4* __restrict__ out) {
    const unsigned v = blockIdx.x * 256u + threadIdx.x;   // exact grid, no loop
    const unsigned p = v / PAIR_F4;            // row-pair index (magic-mul div)
    const int u  = (int)(v - p * PAIR_F4);     // float4 unit within pair [0,285)
    const int b  = (int)(p >> 11);             // / (T/2)
    const int tp = (int)(p & 2047);            // pair's first row is t = 2*tp
    const int base = (2 * tp - PAD) * C;       // source offset of row t
    const int e0 = 4 * u;                      // element offset within pair
    const float* xb = x + (unsigned)b * TC;

    // If element e >= ROW it belongs to row t+1: source -= (ROW - C).
    const int s0 = base + e0     - (e0     >= ROW ? (ROW - C) : 0);
    const int s1 = base + e0 + 2 - (e0 + 2 >= ROW ? (ROW - C) : 0);

    float2 lo = make_float2(0.0f, 0.0f);
    float2 hi = make_float2(0.0f, 0.0f);
    if (s0 >= 0 && s0 < TC) lo = *reinterpret_cast<const float2*>(xb + s0);
    if (s1 >= 0 && s1 < TC) hi = *reinterpret_cast<const float2*>(xb + s1);

    f32x4 val;
    val.x = lo.x; val.y = lo.y; val.z = hi.x; val.w = hi.y;
    out[v] = val;                              // plain write-back store
}

extern "C" void kernel_launch(void* const* d_in, const int* in_sizes, int n_in,
                              void* d_out, int out_size, void* d_ws, size_t ws_size,
                              hipStream_t stream) {
    const float* x = (const float*)d_in[0];
    f32x4* out = (f32x4*)d_out;
    const int block = 256;
    const unsigned grid = TOTAL4 / block;      // 72,900 blocks, exact
    OverlapTimeWindowLayer_kernel<<<grid, block, 0, stream>>>(x, out);
}

// Round 6
// 56.164 us; speedup vs baseline: 1.1520x; 1.1507x over previous
//
#include <hip/hip_runtime.h>

// out[b, t, w, c] = x[b, t + w - 9, c] (zero outside [0, T)), x: [32, 4096, 30] f32.
// Per (b,t) the 570-float output row equals the contiguous x span starting at
// (t-9)*30. Row-pair (t even) = 1140 floats = 285 float4 units, 16B-aligned.
// This round: each WAVE writes a sequential 4KB span via 4 back-to-back 1KB
// wave-stores (thread's units at +64 steps) — fill-kernel-style stream
// clustering for DRAM row-buffer locality. Each 16B store is built from two
// float2 loads (a float2 never straddles a row: 570 even; one check per pair).

typedef float f32x4 __attribute__((ext_vector_type(4)));

constexpr int B   = 32;
constexpr int T   = 4096;          // power of 2
constexpr int C   = 30;
constexpr int PAD = 9;             // W/2
constexpr int ROW = 570;           // W*C floats per output row
constexpr int TC  = T * C;         // 122880 floats per batch of x
constexpr int PAIR_F4 = 285;       // float4 units per row-pair (1140 floats)
constexpr unsigned NPAIRS = (unsigned)B * (T / 2);   // 65536 row-pairs
constexpr unsigned TOTAL4 = NPAIRS * PAIR_F4;        // 18,662,400 float4 units
constexpr int UNROLL = 4;          // wave covers 256 units = 4KB sequential
// TOTAL4 / 256 = 72,900 waves exactly; 4 waves/block -> 18,225 blocks.

__global__ __launch_bounds__(256)
void OverlapTimeWindowLayer_kernel(const float* __restrict__ x,
                                   f32x4* __restrict__ out) {
    const unsigned g    = blockIdx.x * 256u + threadIdx.x;
    const unsigned wave = g >> 6;
    const int      lane = (int)(g & 63u);
    const unsigned vbase = wave * 256u + (unsigned)lane;  // unit for k=0
#pragma unroll
    for (int k = 0; k < UNROLL; ++k) {
        const unsigned v = vbase + (unsigned)(64 * k);  // wave-contiguous 1KB each
        const unsigned p = v / PAIR_F4;            // row-pair index (magic-mul div)
        const int u  = (int)(v - p * PAIR_F4);     // float4 unit within pair [0,285)
        const int b  = (int)(p >> 11);             // / (T/2)
        const int tp = (int)(p & 2047);            // pair's first row is t = 2*tp
        const int base = (2 * tp - PAD) * C;       // source offset of row t
        const int e0 = 4 * u;                      // element offset within pair
        const float* xb = x + (unsigned)b * TC;

        // If element e >= ROW it belongs to row t+1: source -= (ROW - C).
        const int s0 = base + e0     - (e0     >= ROW ? (ROW - C) : 0);
        const int s1 = base + e0 + 2 - (e0 + 2 >= ROW ? (ROW - C) : 0);

        float2 lo = make_float2(0.0f, 0.0f);
        float2 hi = make_float2(0.0f, 0.0f);
        if (s0 >= 0 && s0 < TC) lo = *reinterpret_cast<const float2*>(xb + s0);
        if (s1 >= 0 && s1 < TC) hi = *reinterpret_cast<const float2*>(xb + s1);

        f32x4 val;
        val.x = lo.x; val.y = lo.y; val.z = hi.x; val.w = hi.y;
        out[v] = val;
    }
}

extern "C" void kernel_launch(void* const* d_in, const int* in_sizes, int n_in,
                              void* d_out, int out_size, void* d_ws, size_t ws_size,
                              hipStream_t stream) {
    const float* x = (const float*)d_in[0];
    f32x4* out = (f32x4*)d_out;
    const int block = 256;
    const unsigned grid = TOTAL4 / (256u * (unsigned)UNROLL);  // 18,225 blocks
    OverlapTimeWindowLayer_kernel<<<grid, block, 0, stream>>>(x, out);
}